// Round 8
// baseline (3469.012 us; speedup 1.0000x reference)
//
#include <hip/hip_runtime.h>

// ---------------------------------------------------------------------------
// multiStepModel: LSTM encoder (T=365) -> relu -> constant-input LSTM decoder
// (90 steps) -> relu -> FC.  Persistent cooperative kernel, 1 WG/CU.
// R8: 2-syncthreads step skeleton.  All threads poll member flags (per-wave
// detect, no post-poll sync); h LLC loads issued at detect; x-part MFMA runs
// while they fly; x(t+1) prefetched to registers at loop top; flag publish
// via relaxed AGENT store right after the release sync.  Split-f16 3-term
// MFMA, register cell (acc = i,f,g,o), fast exp/rcp transcendentals.
// ---------------------------------------------------------------------------

namespace {
constexpr int B = 128, T = 365, IN = 64, COV = 256, H = 512, OUTL = 90;
constexpr int GB = 4;            // batch groups (independent barrier quorums)
constexpr int GJ = 64;           // hidden groups
constexpr int NWG = GB * GJ;     // 256 workgroups, 1/CU
constexpr int NT = 256;          // threads per WG (4 waves)
constexpr int BS = B / GB;       // 32 batch rows per WG
constexpr int HU = H / GJ;       // 8 hidden units per WG
constexpr int NR = 4 * HU;       // 32 gate rows per WG (reordered unit*4+gate)
constexpr int NSLOT_H = 64;      // 512/8 16B slots (h part of K)
constexpr int NSLOT = 72;        // + 64/8 slots (x part)
}

using ull = unsigned long long;
typedef __attribute__((ext_vector_type(8))) short short8;
typedef __attribute__((ext_vector_type(8))) _Float16 half8;
typedef __attribute__((ext_vector_type(4))) float f32x4;

__device__ unsigned int g_h[2][B][H];      // packed f16 (hi<<16|lo) hidden state
__device__ float g_part[OUTL][GJ][B];      // per-hidden-group FC partials
__device__ int   g_flag[GB][64];           // per-WG monotonic barrier flags

__device__ __forceinline__ float sigfast(float x) {
  return __builtin_amdgcn_rcpf(1.0f + __expf(-x));   // sat: x<<0 -> 0, x>>0 -> 1
}
__device__ __forceinline__ float tanhfast(float x) {
  return 1.0f - 2.0f * __builtin_amdgcn_rcpf(__expf(2.0f * x) + 1.0f);
}

__device__ __forceinline__ float4 fma4(float4 a, float4 b, float4 c) {
  c.x = fmaf(a.x, b.x, c.x); c.y = fmaf(a.y, b.y, c.y);
  c.z = fmaf(a.z, b.z, c.z); c.w = fmaf(a.w, b.w, c.w);
  return c;
}
__device__ __forceinline__ float hsum4(float4 a) { return (a.x + a.y) + (a.z + a.w); }

__device__ __forceinline__ unsigned int pack_split(float v) {
  _Float16 hi = (_Float16)v;
  _Float16 lo = (_Float16)(v - (float)hi);
  return ((unsigned int)__builtin_bit_cast(unsigned short, hi) << 16) |
         (unsigned int)__builtin_bit_cast(unsigned short, lo);
}
__device__ __forceinline__ float unpack_split(unsigned int u) {
  _Float16 hi = __builtin_bit_cast(_Float16, (unsigned short)(u >> 16));
  _Float16 lo = __builtin_bit_cast(_Float16, (unsigned short)(u & 0xFFFFu));
  return (float)hi + (float)lo;
}

__global__ void __launch_bounds__(256) k_init() {
  int t = threadIdx.x;
  if (t < GB * 64) g_flag[t >> 6][t & 63] = 0;
}

__global__ void __launch_bounds__(NT, 1) k_lstm(
    const float* __restrict__ input, const float* __restrict__ covar,
    const float* __restrict__ W_ih1, const float* __restrict__ W_hh1,
    const float* __restrict__ b1,    const float* __restrict__ W_ih2,
    const float* __restrict__ W_hh2, const float* __restrict__ b2,
    const float* __restrict__ W_fc) {
  // Row r = unit*4 + gate (i,f,g,o).  Slot s of row r stored at s ^ (r&7).
  __shared__ __align__(16) short wH[NR][NSLOT * 8];   // W hi   36.9 KB
  __shared__ __align__(16) short wL[NR][NSLOT * 8];   // W lo   36.9 KB
  __shared__ __align__(16) short bH[BS][NSLOT * 8];   // [h;x] hi
  __shared__ __align__(16) short bL[BS][NSLOT * 8];   // [h;x] lo
  __shared__ float pb_lds[NR][33];                    // covproj+b1 / proj2
  __shared__ float aux[4][16];                        // decoder FC combine

  const int tid = threadIdx.x;
  const int gb  = blockIdx.x & (GB - 1);
  const int gj  = blockIdx.x >> 2;
  const int bg0 = gb * BS;
  const int j0  = gj * HU;

  const int lane  = tid & 63;
  const int wv    = tid >> 6;
  const int rows0 = (wv >> 1) * 16;        // gate-row tile (units (wv>>1)*4..+3)
  const int cols0 = (wv & 1) * 16;         // batch tile
  const int ra    = rows0 + (lane & 15);   // A row
  const int b_l   = cols0 + (lane & 15);   // B row == D col == batch
  const int cc    = lane >> 4;             // k-chunk / gate-quad 0..3
  const int x7    = lane & 7;              // XOR swizzle key (== ra&7 == b_l&7)
  const int u_l   = (wv >> 1) * 4 + cc;    // this lane's unit 0..7

  const int bl = tid >> 3;                 // staging row 0..31
  const int sg = tid & 7;                  // staging phase 0..7
  const int bt = tid & 15;                 // fp32 helper mapping
  const int rt = tid >> 4;

  // ---- all-thread poll: lane l of every wave watches member (tid&63).
  // Wave proceeds when all 64 member flags >= nb (exec-mask reconvergence).
  auto poll = [&](int nb) {
    while (__hip_atomic_load(&g_flag[gb][tid & 63], __ATOMIC_RELAXED,
                             __HIP_MEMORY_SCOPE_AGENT) < nb)
      __builtin_amdgcn_s_sleep(1);
  };
  auto publish = [&](int nb) {
    if (tid == 0)
      __hip_atomic_store(&g_flag[gb][gj], nb, __ATOMIC_RELAXED,
                         __HIP_MEMORY_SCOPE_AGENT);
  };

  // ---- split one 8-float slot into f16 hi/lo W tiles (XOR-swizzled) ----
  auto put_w = [&](int r, int s, const float* src) {
    float4 p0 = ((const float4*)src)[0], p1 = ((const float4*)src)[1];
    float f[8] = {p0.x, p0.y, p0.z, p0.w, p1.x, p1.y, p1.z, p1.w};
    short8 hi, lo;
#pragma unroll
    for (int j = 0; j < 8; ++j) {
      _Float16 h_ = (_Float16)f[j];
      hi[j] = __builtin_bit_cast(short, h_);
      lo[j] = __builtin_bit_cast(short, (_Float16)(f[j] - (float)h_));
    }
    const int s2 = s ^ (r & 7);
    *(short8*)&wH[r][s2 * 8] = hi;
    *(short8*)&wL[r][s2 * 8] = lo;
  };

  // local row r: unit = r>>2, gate = r&3  ->  global W row
  auto wrow = [&](int r) { return (r & 3) * H + j0 + (r >> 2); };

  auto stage_w_hh = [&](const float* Whh) {
    for (int idx = tid; idx < NR * NSLOT_H; idx += NT) {
      const int r = idx >> 6, s = idx & 63;
      put_w(r, s, Whh + (size_t)wrow(r) * H + s * 8);
    }
  };

  // x prefetch (regs) and stage (LDS), slot sg of row bl
  auto load_x_regs = [&](int tn, float4& p0, float4& p1) {
    const float* src = input + ((size_t)(bg0 + bl) * T + tn) * IN + sg * 8;
    p0 = ((const float4*)src)[0];
    p1 = ((const float4*)src)[1];
  };
  auto stage_x_regs = [&](float4 p0, float4 p1) {
    float f[8] = {p0.x, p0.y, p0.z, p0.w, p1.x, p1.y, p1.z, p1.w};
    short8 hi, lo;
#pragma unroll
    for (int j = 0; j < 8; ++j) {
      _Float16 h_ = (_Float16)f[j];
      hi[j] = __builtin_bit_cast(short, h_);
      lo[j] = __builtin_bit_cast(short, (_Float16)(f[j] - (float)h_));
    }
    const int s2 = (NSLOT_H + sg) ^ (bl & 7);
    *(short8*)&bH[bl][s2 * 8] = hi;
    *(short8*)&bL[bl][s2 * 8] = lo;
  };

  // h staging: dense 64B-coalesced LLC loads -> (later) swizzled LDS commit
  auto load_h = [&](int par, ull (&tmp)[32]) {
    const ull* hr = (const ull*)&g_h[par][bg0 + bl][0];   // 256 ull per row
#pragma unroll
    for (int i = 0; i < 32; ++i)
      tmp[i] = __hip_atomic_load(hr + sg + 8 * i, __ATOMIC_RELAXED,
                                 __HIP_MEMORY_SCOPE_AGENT);
  };
  auto commit_h = [&](ull (&tmp)[32]) {
#pragma unroll
    for (int i = 0; i < 32; ++i) {
      const int m = sg + 8 * i;                  // ull index 0..255
      const int s2 = (m >> 2) ^ (bl & 7);        // swizzled 16B slot
      const int p = m & 3;                       // word within slot
      const unsigned u0 = (unsigned)tmp[i], u1 = (unsigned)(tmp[i] >> 32);
      ((unsigned*)&bH[bl][s2 * 8])[p] = (u0 >> 16) | (u1 & 0xFFFF0000u);
      ((unsigned*)&bL[bl][s2 * 8])[p] = (u0 & 0xFFFFu) | (u1 << 16);
    }
  };

  // One MFMA k-block (3-term split product)
  auto mfma_kb = [&](int kb, f32x4& aA, f32x4& aB, f32x4& aC) {
    const int s2 = (kb * 4 + cc) ^ x7;
    const half8 ah = __builtin_bit_cast(half8, *(const short8*)&wH[ra][s2 * 8]);
    const half8 al = __builtin_bit_cast(half8, *(const short8*)&wL[ra][s2 * 8]);
    const half8 bh = __builtin_bit_cast(half8, *(const short8*)&bH[b_l][s2 * 8]);
    const half8 bo = __builtin_bit_cast(half8, *(const short8*)&bL[b_l][s2 * 8]);
    aA = __builtin_amdgcn_mfma_f32_16x16x32_f16(ah, bh, aA, 0, 0, 0);
    aB = __builtin_amdgcn_mfma_f32_16x16x32_f16(ah, bo, aB, 0, 0, 0);
    aC = __builtin_amdgcn_mfma_f32_16x16x32_f16(al, bh, aC, 0, 0, 0);
  };

  // ======================= one-time setup =======================
  stage_w_hh(W_hh1);
  for (int idx = tid; idx < NR * 8; idx += NT) {   // x cols of W_ih1
    const int r = idx >> 3;
    put_w(r, NSLOT_H + (idx & 7),
          W_ih1 + (size_t)wrow(r) * (IN + COV) + (idx & 7) * 8);
  }
  {  // covariate projection + b1 -> pb_lds (fp32, once)
    const int r0 = rt, r1 = rt + 16;
    const int row0 = wrow(r0), row1 = wrow(r1);
    const float4* c0 = (const float4*)(covar + (size_t)(bg0 + bt) * COV);
    const float4* c1 = (const float4*)(covar + (size_t)(bg0 + bt + 16) * COV);
    const float4* w0 = (const float4*)(W_ih1 + (size_t)row0 * (IN + COV) + IN);
    const float4* w1 = (const float4*)(W_ih1 + (size_t)row1 * (IN + COV) + IN);
    float4 a00 = {0, 0, 0, 0}, a01 = a00, a10 = a00, a11 = a00;
    for (int k = 0; k < COV / 4; ++k) {
      float4 va = c0[k], vb = c1[k], wa = w0[k], wb = w1[k];
      a00 = fma4(va, wa, a00); a01 = fma4(va, wb, a01);
      a10 = fma4(vb, wa, a10); a11 = fma4(vb, wb, a11);
    }
    pb_lds[r0][bt]      = hsum4(a00) + b1[row0];
    pb_lds[r1][bt]      = hsum4(a01) + b1[row1];
    pb_lds[r0][bt + 16] = hsum4(a10) + b1[row0];
    pb_lds[r1][bt + 16] = hsum4(a11) + b1[row1];
  }
  {  // stage x_0
    float4 p0, p1;
    load_x_regs(0, p0, p1);
    stage_x_regs(p0, p1);
  }
  __syncthreads();   // wH/wL + pb_lds + x_0 ready

  float pb4[4];
#pragma unroll
  for (int q = 0; q < 4; ++q) pb4[q] = pb_lds[rows0 + cc * 4 + q][b_l];

  float c_state = 0.0f;

  // register cell: acc[q] + pb4[q] are the i,f,g,o pre-activations
  auto cellp = [&](const f32x4& acc) -> float {
    const float gi = acc[0] + pb4[0];
    const float gf = acc[1] + pb4[1];
    const float gg = acc[2] + pb4[2];
    const float go = acc[3] + pb4[3];
    c_state = sigfast(gf) * c_state + sigfast(gi) * tanhfast(gg);
    return sigfast(go) * tanhfast(c_state);
  };

  // =================== encoder: 365 steps ===================
  for (int t = 0; t < T; ++t) {
    if (t > 0) poll(t);                        // h(t) ready everywhere
    ull tmp[32];
    if (t > 0) load_h(t & 1, tmp);             // issue LLC loads at detect
    float4 xp0, xp1;
    const bool havex = (t + 1 < T);
    if (havex) load_x_regs(t + 1, xp0, xp1);   // prefetch next x (cached)
    f32x4 aA = {0.f, 0.f, 0.f, 0.f}, aB = aA, aC = aA;
#pragma unroll
    for (int kb = 16; kb < 18; ++kb) mfma_kb(kb, aA, aB, aC);  // x_t part
    if (t > 0) commit_h(tmp);                  // waitcnt + LDS writes
    __syncthreads();                           // sync1: B h-tile ready
    if (t > 0) {
#pragma unroll
      for (int kb = 0; kb < 16; ++kb) mfma_kb(kb, aA, aB, aC); // h part
    }
    f32x4 acc;
#pragma unroll
    for (int q = 0; q < 4; ++q) acc[q] = aA[q] + aB[q] + aC[q];
    float hv = cellp(acc);
    if (t == T - 1) hv = fmaxf(hv, 0.0f);      // relu(h_enc)
    __hip_atomic_store(&g_h[(t + 1) & 1][bg0 + b_l][j0 + u_l], pack_split(hv),
                       __ATOMIC_RELAXED, __HIP_MEMORY_SCOPE_AGENT);
    if (havex) stage_x_regs(xp0, xp1);         // x_{t+1} -> LDS
    __syncthreads();                           // sync2: stores+staging drained
    publish(t + 1);
  }

  // ====== transition: proj2 = [relu(h_enc),covar] @ W_ih2^T + b2 (fp32) ======
  poll(T);                                     // all h_enc written
  {
    const int b0 = bt, b1v = bt + 16;
    const int r0 = rt, r1 = rt + 16;
    const int row0 = wrow(r0), row1 = wrow(r1);
    const float* w0 = W_ih2 + (size_t)row0 * (H + COV);
    const float* w1 = W_ih2 + (size_t)row1 * (H + COV);
    const ull* h0 = (const ull*)&g_h[1][bg0 + b0][0];
    const ull* h1 = (const ull*)&g_h[1][bg0 + b1v][0];
    float a00 = 0.f, a01 = 0.f, a10 = 0.f, a11 = 0.f;
    for (int m = 0; m < H / 2; ++m) {   // h part from packed LLC state
      const ull v0 = __hip_atomic_load(h0 + m, __ATOMIC_RELAXED,
                                       __HIP_MEMORY_SCOPE_AGENT);
      const ull v1 = __hip_atomic_load(h1 + m, __ATOMIC_RELAXED,
                                       __HIP_MEMORY_SCOPE_AGENT);
      const float h00 = unpack_split((unsigned)v0);
      const float h01 = unpack_split((unsigned)(v0 >> 32));
      const float h10 = unpack_split((unsigned)v1);
      const float h11 = unpack_split((unsigned)(v1 >> 32));
      const float wa0 = w0[2 * m], wa1 = w0[2 * m + 1];
      const float wb0 = w1[2 * m], wb1 = w1[2 * m + 1];
      a00 += h00 * wa0 + h01 * wa1;  a01 += h00 * wb0 + h01 * wb1;
      a10 += h10 * wa0 + h11 * wa1;  a11 += h10 * wb0 + h11 * wb1;
    }
    {  // covar part (fp32, cache-hot)
      const float4* c0 = (const float4*)(covar + (size_t)(bg0 + b0) * COV);
      const float4* c1 = (const float4*)(covar + (size_t)(bg0 + b1v) * COV);
      const float4* W0 = (const float4*)w0;
      const float4* W1 = (const float4*)w1;
      float4 s00 = {0, 0, 0, 0}, s01 = s00, s10 = s00, s11 = s00;
      for (int k = 0; k < COV / 4; ++k) {
        float4 ha = c0[k], hb = c1[k], wa = W0[H / 4 + k], wb = W1[H / 4 + k];
        s00 = fma4(ha, wa, s00); s01 = fma4(ha, wb, s01);
        s10 = fma4(hb, wa, s10); s11 = fma4(hb, wb, s11);
      }
      a00 += hsum4(s00); a01 += hsum4(s01);
      a10 += hsum4(s10); a11 += hsum4(s11);
    }
    pb_lds[r0][b0]  = a00 + b2[row0];
    pb_lds[r1][b0]  = a01 + b2[row1];
    pb_lds[r0][b1v] = a10 + b2[row0];
    pb_lds[r1][b1v] = a11 + b2[row1];
  }
  stage_w_hh(W_hh2);        // decoder recurrent weights over encoder ones
  __syncthreads();          // drains g_h reads (vmcnt) + LDS ready
  publish(T + 1);           // "this WG is done reading h_enc"
#pragma unroll
  for (int q = 0; q < 4; ++q) pb4[q] = pb_lds[rows0 + cc * 4 + q][b_l];
  const float wfc = W_fc[j0 + u_l];
  c_state = 0.0f;

  // =================== decoder: 90 steps ===================
  for (int ot = 0; ot < OUTL; ++ot) {
    poll(T + 1 + ot);                          // h(ot) ready (ot=0: h_enc free)
    ull tmp[32];
    if (ot > 0) {
      load_h(ot & 1, tmp);
      commit_h(tmp);
    }
    __syncthreads();                           // sync1
    f32x4 aA = {0.f, 0.f, 0.f, 0.f}, aB = aA, aC = aA;
    if (ot > 0) {
#pragma unroll
      for (int kb = 0; kb < 16; ++kb) mfma_kb(kb, aA, aB, aC);
    }
    f32x4 acc;
#pragma unroll
    for (int q = 0; q < 4; ++q) acc[q] = aA[q] + aB[q] + aC[q];
    const float hv = cellp(acc);               // ot==0: gates = proj2 only
    __hip_atomic_store(&g_h[(ot + 1) & 1][bg0 + b_l][j0 + u_l], pack_split(hv),
                       __ATOMIC_RELAXED, __HIP_MEMORY_SCOPE_AGENT);
    // FC partial: relu(hv)*wfc summed over this WG's 8 units per batch row
    float fcv = fmaxf(hv, 0.0f) * wfc;
    fcv += __shfl_xor(fcv, 16);
    fcv += __shfl_xor(fcv, 32);                // sum over the 4 unit-lanes
    if (lane < 16) aux[wv][lane] = fcv;
    __syncthreads();                           // sync2: h' stores + aux drained
    publish(T + 2 + ot);
    if (tid < 32)                              // no step-dependency on g_part
      g_part[ot][gj][bg0 + tid] =
          aux[tid >> 4][tid & 15] + aux[(tid >> 4) + 2][tid & 15];
  }
}

__global__ void __launch_bounds__(256) k_reduce(const float* __restrict__ b_fc,
                                                float* __restrict__ out) {
  int id = blockIdx.x * 256 + threadIdx.x;
  if (id >= B * OUTL) return;
  int b = id / OUTL, ot = id - b * OUTL;
  float s = b_fc[0];
#pragma unroll 8
  for (int g = 0; g < GJ; ++g) s += g_part[ot][g][b];
  out[id] = s;   // out[b][ot], row-major == id
}

extern "C" void kernel_launch(void* const* d_in, const int* in_sizes, int n_in,
                              void* d_out, int out_size, void* d_ws, size_t ws_size,
                              hipStream_t stream) {
  (void)in_sizes; (void)n_in; (void)d_ws; (void)ws_size; (void)out_size;
  const float* input = (const float*)d_in[0];
  const float* covar = (const float*)d_in[1];
  const float* W_ih1 = (const float*)d_in[2];
  const float* W_hh1 = (const float*)d_in[3];
  const float* b1    = (const float*)d_in[4];
  const float* W_ih2 = (const float*)d_in[5];
  const float* W_hh2 = (const float*)d_in[6];
  const float* b2    = (const float*)d_in[7];
  const float* W_fc  = (const float*)d_in[8];
  const float* b_fc  = (const float*)d_in[9];

  k_init<<<dim3(1), dim3(256), 0, stream>>>();
  k_lstm<<<dim3(NWG), dim3(NT), 0, stream>>>(input, covar, W_ih1, W_hh1, b1,
                                             W_ih2, W_hh2, b2, W_fc);
  k_reduce<<<dim3((B * OUTL + 255) / 256), dim3(256), 0, stream>>>(
      b_fc, (float*)d_out);
}

// Round 9
// 2691.907 us; speedup vs baseline: 1.2887x; 1.2887x over previous
//
#include <hip/hip_runtime.h>

// ---------------------------------------------------------------------------
// multiStepModel: LSTM encoder (T=365) -> relu -> constant-input LSTM decoder
// (90 steps) -> relu -> FC.  Persistent cooperative kernel, 1 WG/CU.
// R9: per-wave disjoint flag polling.  Wave wv polls ONLY the 16 producers of
// its K-quarter (one 64B flag line/wave -> same total poll traffic as R7 but
// detection+load-issue are wave-parallel), stages its quarter immediately on
// detect, then sync1 joins waves (union of 4x16 polls = all-64 verified ->
// WAR-safe before any h' store).  2 syncthreads/step.  Split-f16 3-term MFMA,
// register LSTM cell in MFMA accumulators, fast exp/rcp transcendentals.
// ---------------------------------------------------------------------------

namespace {
constexpr int B = 128, T = 365, IN = 64, COV = 256, H = 512, OUTL = 90;
constexpr int GB = 4;            // batch groups (independent barrier quorums)
constexpr int GJ = 64;           // hidden groups
constexpr int NWG = GB * GJ;     // 256 workgroups, 1/CU
constexpr int NT = 256;          // threads per WG (4 waves)
constexpr int BS = B / GB;       // 32 batch rows per WG
constexpr int HU = H / GJ;       // 8 hidden units per WG
constexpr int NR = 4 * HU;       // 32 gate rows per WG (reordered unit*4+gate)
constexpr int NSLOT_H = 64;      // 512/8 16B slots (h part of K)
constexpr int NSLOT = 72;        // + 64/8 slots (x part)
}

using ull = unsigned long long;
typedef __attribute__((ext_vector_type(8))) short short8;
typedef __attribute__((ext_vector_type(8))) _Float16 half8;
typedef __attribute__((ext_vector_type(4))) float f32x4;

__device__ unsigned int g_h[2][B][H];          // packed f16 (hi<<16|lo) state
__device__ float g_part[OUTL][GJ][B];          // per-hidden-group FC partials
__device__ __align__(256) int g_flag[GB][64];  // per-WG monotonic flags

__device__ __forceinline__ float sigfast(float x) {
  return __builtin_amdgcn_rcpf(1.0f + __expf(-x));
}
__device__ __forceinline__ float tanhfast(float x) {
  return 1.0f - 2.0f * __builtin_amdgcn_rcpf(__expf(2.0f * x) + 1.0f);
}

__device__ __forceinline__ float4 fma4(float4 a, float4 b, float4 c) {
  c.x = fmaf(a.x, b.x, c.x); c.y = fmaf(a.y, b.y, c.y);
  c.z = fmaf(a.z, b.z, c.z); c.w = fmaf(a.w, b.w, c.w);
  return c;
}
__device__ __forceinline__ float hsum4(float4 a) { return (a.x + a.y) + (a.z + a.w); }

__device__ __forceinline__ unsigned int pack_split(float v) {
  _Float16 hi = (_Float16)v;
  _Float16 lo = (_Float16)(v - (float)hi);
  return ((unsigned int)__builtin_bit_cast(unsigned short, hi) << 16) |
         (unsigned int)__builtin_bit_cast(unsigned short, lo);
}
__device__ __forceinline__ float unpack_split(unsigned int u) {
  _Float16 hi = __builtin_bit_cast(_Float16, (unsigned short)(u >> 16));
  _Float16 lo = __builtin_bit_cast(_Float16, (unsigned short)(u & 0xFFFFu));
  return (float)hi + (float)lo;
}

__global__ void __launch_bounds__(256) k_init() {
  int t = threadIdx.x;
  if (t < GB * 64) g_flag[t >> 6][t & 63] = 0;
}

__global__ void __launch_bounds__(NT, 1) k_lstm(
    const float* __restrict__ input, const float* __restrict__ covar,
    const float* __restrict__ W_ih1, const float* __restrict__ W_hh1,
    const float* __restrict__ b1,    const float* __restrict__ W_ih2,
    const float* __restrict__ W_hh2, const float* __restrict__ b2,
    const float* __restrict__ W_fc) {
  // Row r = unit*4 + gate (i,f,g,o).  Slot s of row r stored at s ^ (r&7).
  __shared__ __align__(16) short wH[NR][NSLOT * 8];   // W hi   36.9 KB
  __shared__ __align__(16) short wL[NR][NSLOT * 8];   // W lo   36.9 KB
  __shared__ __align__(16) short bH[BS][NSLOT * 8];   // [h;x] hi
  __shared__ __align__(16) short bL[BS][NSLOT * 8];   // [h;x] lo
  __shared__ float pb_lds[NR][33];                    // covproj+b1 / proj2
  __shared__ float aux[4][16];                        // decoder FC combine

  const int tid = threadIdx.x;
  const int gb  = blockIdx.x & (GB - 1);
  const int gj  = blockIdx.x >> 2;
  const int bg0 = gb * BS;
  const int j0  = gj * HU;

  const int lane  = tid & 63;
  const int wv    = tid >> 6;
  const int rows0 = (wv >> 1) * 16;        // gate-row tile
  const int cols0 = (wv & 1) * 16;         // batch tile
  const int ra    = rows0 + (lane & 15);   // A row
  const int b_l   = cols0 + (lane & 15);   // B row == D col == batch
  const int cc    = lane >> 4;             // k-chunk / gate-quad 0..3
  const int x7    = lane & 7;              // XOR swizzle key
  const int u_l   = (wv >> 1) * 4 + cc;    // this lane's unit 0..7

  const int bl = tid >> 3;                 // x staging row 0..31
  const int sg = tid & 7;                  // x staging phase 0..7
  const int bt = tid & 15;                 // fp32 helper mapping
  const int rt = tid >> 4;

  // ---- per-wave poll: wave wv watches ONLY producers [wv*16, wv*16+16)
  // (one 64B flag line).  Union over the 4 waves at the next barrier = all
  // 64 members verified (WAR-safe: h' stores happen after that barrier).
  const int watch = (wv << 4) + (lane & 15);
  auto pollw = [&](int nb) {
    while (__hip_atomic_load(&g_flag[gb][watch], __ATOMIC_RELAXED,
                             __HIP_MEMORY_SCOPE_AGENT) < nb)
      __builtin_amdgcn_s_sleep(1);
  };
  auto publish = [&](int nb) {
    if (tid == 0)
      __hip_atomic_store(&g_flag[gb][gj], nb, __ATOMIC_RELAXED,
                         __HIP_MEMORY_SCOPE_AGENT);
  };

  // ---- split one 8-float slot into f16 hi/lo W tiles (XOR-swizzled) ----
  auto put_w = [&](int r, int s, const float* src) {
    float4 p0 = ((const float4*)src)[0], p1 = ((const float4*)src)[1];
    float f[8] = {p0.x, p0.y, p0.z, p0.w, p1.x, p1.y, p1.z, p1.w};
    short8 hi, lo;
#pragma unroll
    for (int j = 0; j < 8; ++j) {
      _Float16 h_ = (_Float16)f[j];
      hi[j] = __builtin_bit_cast(short, h_);
      lo[j] = __builtin_bit_cast(short, (_Float16)(f[j] - (float)h_));
    }
    const int s2 = s ^ (r & 7);
    *(short8*)&wH[r][s2 * 8] = hi;
    *(short8*)&wL[r][s2 * 8] = lo;
  };

  auto wrow = [&](int r) { return (r & 3) * H + j0 + (r >> 2); };

  auto stage_w_hh = [&](const float* Whh) {
    for (int idx = tid; idx < NR * NSLOT_H; idx += NT) {
      const int r = idx >> 6, s = idx & 63;
      put_w(r, s, Whh + (size_t)wrow(r) * H + s * 8);
    }
  };

  // x prefetch (regs) and stage (LDS), slot sg of row bl
  auto load_x_regs = [&](int tn, float4& p0, float4& p1) {
    const float* src = input + ((size_t)(bg0 + bl) * T + tn) * IN + sg * 8;
    p0 = ((const float4*)src)[0];
    p1 = ((const float4*)src)[1];
  };
  auto stage_x_regs = [&](float4 p0, float4 p1) {
    float f[8] = {p0.x, p0.y, p0.z, p0.w, p1.x, p1.y, p1.z, p1.w};
    short8 hi, lo;
#pragma unroll
    for (int j = 0; j < 8; ++j) {
      _Float16 h_ = (_Float16)f[j];
      hi[j] = __builtin_bit_cast(short, h_);
      lo[j] = __builtin_bit_cast(short, (_Float16)(f[j] - (float)h_));
    }
    const int s2 = (NSLOT_H + sg) ^ (bl & 7);
    *(short8*)&bH[bl][s2 * 8] = hi;
    *(short8*)&bL[bl][s2 * 8] = lo;
  };

  // ---- per-wave h staging: wave wv stages K-quarter [wv*128 u32) of ALL
  // 32 rows (the columns its 16 polled producers wrote).  Coalesced: per
  // instruction 16 lanes x 8B = 128B contiguous per row.
  const int rg = lane >> 4;        // row group 0..3
  const int pp = lane & 15;        // 16B phase 0..15
  auto stage_hw = [&](int par) {
    ull tmp[32];
    const ull* base = (const ull*)&g_h[par][bg0][0];    // row stride 256 ull
#pragma unroll
    for (int j = 0; j < 8; ++j)
#pragma unroll
      for (int i = 0; i < 4; ++i)
        tmp[j * 4 + i] =
            __hip_atomic_load(base + (size_t)(rg + 4 * j) * 256 +
                                  (wv * 64 + i * 16 + pp),
                              __ATOMIC_RELAXED, __HIP_MEMORY_SCOPE_AGENT);
#pragma unroll
    for (int j = 0; j < 8; ++j) {
      const int r = rg + 4 * j;
#pragma unroll
      for (int i = 0; i < 4; ++i) {
        const int m = wv * 64 + i * 16 + pp;       // ull index 0..255
        const int s2 = (m >> 2) ^ (r & 7);         // swizzled 16B slot
        const unsigned u0 = (unsigned)tmp[j * 4 + i];
        const unsigned u1 = (unsigned)(tmp[j * 4 + i] >> 32);
        ((unsigned*)&bH[r][s2 * 8])[m & 3] = (u0 >> 16) | (u1 & 0xFFFF0000u);
        ((unsigned*)&bL[r][s2 * 8])[m & 3] = (u0 & 0xFFFFu) | (u1 << 16);
      }
    }
  };

  // One MFMA k-block (3-term split product)
  auto mfma_kb = [&](int kb, f32x4& aA, f32x4& aB, f32x4& aC) {
    const int s2 = (kb * 4 + cc) ^ x7;
    const half8 ah = __builtin_bit_cast(half8, *(const short8*)&wH[ra][s2 * 8]);
    const half8 al = __builtin_bit_cast(half8, *(const short8*)&wL[ra][s2 * 8]);
    const half8 bh = __builtin_bit_cast(half8, *(const short8*)&bH[b_l][s2 * 8]);
    const half8 bo = __builtin_bit_cast(half8, *(const short8*)&bL[b_l][s2 * 8]);
    aA = __builtin_amdgcn_mfma_f32_16x16x32_f16(ah, bh, aA, 0, 0, 0);
    aB = __builtin_amdgcn_mfma_f32_16x16x32_f16(ah, bo, aB, 0, 0, 0);
    aC = __builtin_amdgcn_mfma_f32_16x16x32_f16(al, bh, aC, 0, 0, 0);
  };

  // ======================= one-time setup =======================
  stage_w_hh(W_hh1);
  for (int idx = tid; idx < NR * 8; idx += NT) {   // x cols of W_ih1
    const int r = idx >> 3;
    put_w(r, NSLOT_H + (idx & 7),
          W_ih1 + (size_t)wrow(r) * (IN + COV) + (idx & 7) * 8);
  }
  {  // covariate projection + b1 -> pb_lds (fp32, once)
    const int r0 = rt, r1 = rt + 16;
    const int row0 = wrow(r0), row1 = wrow(r1);
    const float4* c0 = (const float4*)(covar + (size_t)(bg0 + bt) * COV);
    const float4* c1 = (const float4*)(covar + (size_t)(bg0 + bt + 16) * COV);
    const float4* w0 = (const float4*)(W_ih1 + (size_t)row0 * (IN + COV) + IN);
    const float4* w1 = (const float4*)(W_ih1 + (size_t)row1 * (IN + COV) + IN);
    float4 a00 = {0, 0, 0, 0}, a01 = a00, a10 = a00, a11 = a00;
    for (int k = 0; k < COV / 4; ++k) {
      float4 va = c0[k], vb = c1[k], wa = w0[k], wb = w1[k];
      a00 = fma4(va, wa, a00); a01 = fma4(va, wb, a01);
      a10 = fma4(vb, wa, a10); a11 = fma4(vb, wb, a11);
    }
    pb_lds[r0][bt]      = hsum4(a00) + b1[row0];
    pb_lds[r1][bt]      = hsum4(a01) + b1[row1];
    pb_lds[r0][bt + 16] = hsum4(a10) + b1[row0];
    pb_lds[r1][bt + 16] = hsum4(a11) + b1[row1];
  }
  {  // stage x_0
    float4 p0, p1;
    load_x_regs(0, p0, p1);
    stage_x_regs(p0, p1);
  }
  __syncthreads();   // wH/wL + pb_lds + x_0 ready

  float pb4[4];
#pragma unroll
  for (int q = 0; q < 4; ++q) pb4[q] = pb_lds[rows0 + cc * 4 + q][b_l];

  float c_state = 0.0f;

  auto cellp = [&](const f32x4& acc) -> float {
    const float gi = acc[0] + pb4[0];
    const float gf = acc[1] + pb4[1];
    const float gg = acc[2] + pb4[2];
    const float go = acc[3] + pb4[3];
    c_state = sigfast(gf) * c_state + sigfast(gi) * tanhfast(gg);
    return sigfast(go) * tanhfast(c_state);
  };

  // =================== encoder: 365 steps ===================
  for (int t = 0; t < T; ++t) {
    if (t > 0) {
      pollw(t);                 // wave's 16 producers ready -> load now
      stage_hw(t & 1);
    }
    float4 xp0, xp1;
    const bool havex = (t + 1 < T);
    if (havex) load_x_regs(t + 1, xp0, xp1);   // overlaps MFMA below
    __syncthreads();            // sync1: all waves polled+staged (union=64)
    f32x4 aA = {0.f, 0.f, 0.f, 0.f}, aB = aA, aC = aA;
#pragma unroll
    for (int kb = 16; kb < 18; ++kb) mfma_kb(kb, aA, aB, aC);  // x part
    if (t > 0) {
#pragma unroll
      for (int kb = 0; kb < 16; ++kb) mfma_kb(kb, aA, aB, aC); // h part
    }
    f32x4 acc;
#pragma unroll
    for (int q = 0; q < 4; ++q) acc[q] = aA[q] + aB[q] + aC[q];
    float hv = cellp(acc);
    if (t == T - 1) hv = fmaxf(hv, 0.0f);      // relu(h_enc)
    __hip_atomic_store(&g_h[(t + 1) & 1][bg0 + b_l][j0 + u_l], pack_split(hv),
                       __ATOMIC_RELAXED, __HIP_MEMORY_SCOPE_AGENT);
    __syncthreads();            // sync2: h' stores (+x loads) drained
    publish(t + 1);
    if (havex) stage_x_regs(xp0, xp1);   // x_{t+1} -> LDS (read after sync1)
  }

  // ====== transition: proj2 = [relu(h_enc),covar] @ W_ih2^T + b2 (fp32) ======
  pollw(T);
  __syncthreads();              // union: all 64 h_enc producers done
  {
    const int b0 = bt, b1v = bt + 16;
    const int r0 = rt, r1 = rt + 16;
    const int row0 = wrow(r0), row1 = wrow(r1);
    const float* w0 = W_ih2 + (size_t)row0 * (H + COV);
    const float* w1 = W_ih2 + (size_t)row1 * (H + COV);
    const ull* h0 = (const ull*)&g_h[1][bg0 + b0][0];
    const ull* h1 = (const ull*)&g_h[1][bg0 + b1v][0];
    float a00 = 0.f, a01 = 0.f, a10 = 0.f, a11 = 0.f;
    for (int m = 0; m < H / 2; ++m) {   // h part from packed LLC state
      const ull v0 = __hip_atomic_load(h0 + m, __ATOMIC_RELAXED,
                                       __HIP_MEMORY_SCOPE_AGENT);
      const ull v1 = __hip_atomic_load(h1 + m, __ATOMIC_RELAXED,
                                       __HIP_MEMORY_SCOPE_AGENT);
      const float h00 = unpack_split((unsigned)v0);
      const float h01 = unpack_split((unsigned)(v0 >> 32));
      const float h10 = unpack_split((unsigned)v1);
      const float h11 = unpack_split((unsigned)(v1 >> 32));
      const float wa0 = w0[2 * m], wa1 = w0[2 * m + 1];
      const float wb0 = w1[2 * m], wb1 = w1[2 * m + 1];
      a00 += h00 * wa0 + h01 * wa1;  a01 += h00 * wb0 + h01 * wb1;
      a10 += h10 * wa0 + h11 * wa1;  a11 += h10 * wb0 + h11 * wb1;
    }
    {  // covar part (fp32, cache-hot)
      const float4* c0 = (const float4*)(covar + (size_t)(bg0 + b0) * COV);
      const float4* c1 = (const float4*)(covar + (size_t)(bg0 + b1v) * COV);
      const float4* W0 = (const float4*)w0;
      const float4* W1 = (const float4*)w1;
      float4 s00 = {0, 0, 0, 0}, s01 = s00, s10 = s00, s11 = s00;
      for (int k = 0; k < COV / 4; ++k) {
        float4 ha = c0[k], hb = c1[k], wa = W0[H / 4 + k], wb = W1[H / 4 + k];
        s00 = fma4(ha, wa, s00); s01 = fma4(ha, wb, s01);
        s10 = fma4(hb, wa, s10); s11 = fma4(hb, wb, s11);
      }
      a00 += hsum4(s00); a01 += hsum4(s01);
      a10 += hsum4(s10); a11 += hsum4(s11);
    }
    pb_lds[r0][b0]  = a00 + b2[row0];
    pb_lds[r1][b0]  = a01 + b2[row1];
    pb_lds[r0][b1v] = a10 + b2[row0];
    pb_lds[r1][b1v] = a11 + b2[row1];
  }
  stage_w_hh(W_hh2);            // decoder recurrent weights over encoder ones
  __syncthreads();              // drains g_h reads + publishes LDS
  publish(T + 1);               // "done reading h_enc buffer"
#pragma unroll
  for (int q = 0; q < 4; ++q) pb4[q] = pb_lds[rows0 + cc * 4 + q][b_l];
  const float wfc = W_fc[j0 + u_l];
  c_state = 0.0f;

  // =================== decoder: 90 steps ===================
  for (int ot = 0; ot < OUTL; ++ot) {
    pollw(T + 1 + ot);          // ot=0: gates buffer-1 WAR vs transition reads
    if (ot > 0) stage_hw(ot & 1);
    __syncthreads();            // sync1 (union = all 64 verified)
    f32x4 aA = {0.f, 0.f, 0.f, 0.f}, aB = aA, aC = aA;
    if (ot > 0) {
#pragma unroll
      for (int kb = 0; kb < 16; ++kb) mfma_kb(kb, aA, aB, aC);
    }
    f32x4 acc;
#pragma unroll
    for (int q = 0; q < 4; ++q) acc[q] = aA[q] + aB[q] + aC[q];
    const float hv = cellp(acc);             // ot==0: gates = proj2 only
    __hip_atomic_store(&g_h[(ot + 1) & 1][bg0 + b_l][j0 + u_l], pack_split(hv),
                       __ATOMIC_RELAXED, __HIP_MEMORY_SCOPE_AGENT);
    // FC partial: relu(hv)*wfc summed over this WG's 8 units per batch row
    float fcv = fmaxf(hv, 0.0f) * wfc;
    fcv += __shfl_xor(fcv, 16);
    fcv += __shfl_xor(fcv, 32);              // sum over the 4 unit-lanes
    if (lane < 16) aux[wv][lane] = fcv;
    __syncthreads();            // sync2: h' stores + aux drained
    publish(T + 2 + ot);
    if (tid < 32)               // off the critical path
      g_part[ot][gj][bg0 + tid] =
          aux[tid >> 4][tid & 15] + aux[(tid >> 4) + 2][tid & 15];
  }
}

__global__ void __launch_bounds__(256) k_reduce(const float* __restrict__ b_fc,
                                                float* __restrict__ out) {
  int id = blockIdx.x * 256 + threadIdx.x;
  if (id >= B * OUTL) return;
  int b = id / OUTL, ot = id - b * OUTL;
  float s = b_fc[0];
#pragma unroll 8
  for (int g = 0; g < GJ; ++g) s += g_part[ot][g][b];
  out[id] = s;   // out[b][ot], row-major == id
}

extern "C" void kernel_launch(void* const* d_in, const int* in_sizes, int n_in,
                              void* d_out, int out_size, void* d_ws, size_t ws_size,
                              hipStream_t stream) {
  (void)in_sizes; (void)n_in; (void)d_ws; (void)ws_size; (void)out_size;
  const float* input = (const float*)d_in[0];
  const float* covar = (const float*)d_in[1];
  const float* W_ih1 = (const float*)d_in[2];
  const float* W_hh1 = (const float*)d_in[3];
  const float* b1    = (const float*)d_in[4];
  const float* W_ih2 = (const float*)d_in[5];
  const float* W_hh2 = (const float*)d_in[6];
  const float* b2    = (const float*)d_in[7];
  const float* W_fc  = (const float*)d_in[8];
  const float* b_fc  = (const float*)d_in[9];

  k_init<<<dim3(1), dim3(256), 0, stream>>>();
  k_lstm<<<dim3(NWG), dim3(NT), 0, stream>>>(input, covar, W_ih1, W_hh1, b1,
                                             W_ih2, W_hh2, b2, W_fc);
  k_reduce<<<dim3((B * OUTL + 255) / 256), dim3(256), 0, stream>>>(
      b_fc, (float*)d_out);
}